// Round 9
// baseline (182.019 us; speedup 1.0000x reference)
//
#include <hip/hip_runtime.h>
#include <stdint.h>
#include <math.h>

#define C_NUM 65536
#define NPT 24

typedef float nfloat4 __attribute__((ext_vector_type(4)));  // native vec for nontemporal builtin

static __host__ __device__ __forceinline__ void tf2x32(uint32_t k0, uint32_t k1,
                                                       uint32_t& x0, uint32_t& x1) {
  const uint32_t ks2 = k0 ^ k1 ^ 0x1BD11BDAu;
#define TF_R(r) { x0 += x1; x1 = (x1 << (r)) | (x1 >> (32 - (r))); x1 ^= x0; }
  x0 += k0; x1 += k1;
  TF_R(13) TF_R(15) TF_R(26) TF_R(6)
  x0 += k1;  x1 += ks2 + 1u;
  TF_R(17) TF_R(29) TF_R(16) TF_R(24)
  x0 += ks2; x1 += k0 + 2u;
  TF_R(13) TF_R(15) TF_R(26) TF_R(6)
  x0 += k0;  x1 += k1 + 3u;
  TF_R(17) TF_R(29) TF_R(16) TF_R(24)
  x0 += k1;  x1 += ks2 + 4u;
  TF_R(13) TF_R(15) TF_R(26) TF_R(6)
  x0 += ks2; x1 += k0 + 5u;
#undef TF_R
}

// f32 uniform [0,1): x64-OFF partitionable path. VALIDATED R1-R8 — do not touch.
__device__ __forceinline__ float jax_u01f(uint32_t ka, uint32_t kb, uint32_t idx) {
  uint32_t x0 = 0u, x1 = idx;
  tf2x32(ka, kb, x0, x1);
  const uint32_t bits = x0 ^ x1;
  return __fadd_rn(__uint_as_float((bits >> 9) | 0x3f800000u), -1.0f);
}

// XLA:CPU GenerateVF32Exp bitwise replica. VALIDATED — do not touch.
__device__ __forceinline__ float xla_vf32_exp(float x) {
  float xc = fminf(x, 88.3762626647950f);     // exp_hi
  xc = fmaxf(xc, -87.3365478515625f);         // exp_lo
  const float fx = floorf(fmaf(xc, 1.44269504088896341f, 0.5f));
  float r = fmaf(fx, -0.693359375f, xc);      // cephes_exp_C1
  r = fmaf(fx, 2.12194440e-4f, r);            // -C2
  const float z = __fmul_rn(r, r);
  float y = 1.9875691500e-4f;                 // p0
  y = fmaf(y, r, 1.3981999507e-3f);           // p1
  y = fmaf(y, r, 8.3334519073e-3f);           // p2
  y = fmaf(y, r, 4.1665795894e-2f);           // p3
  y = fmaf(y, r, 1.6666665459e-1f);           // p4
  y = fmaf(y, r, 5.0000001201e-1f);           // p5
  y = fmaf(y, z, r);
  y = __fadd_rn(y, 1.0f);
  const int n = (int)fx;                      // our inputs: |fx| <= ~9, exact scale
  return __fmul_rn(y, __uint_as_float((uint32_t)(127 + n) << 23));
}

// ---------------- Kernel A: one thread per (row,k) -> tab (R4-validated) ------
__global__ void __launch_bounds__(256) wkern(const float* __restrict__ params,
                                             int* __restrict__ tab,
                                             uint32_t kr0, uint32_t kr1,
                                             uint32_t kg0, uint32_t kg1) {
  const int g    = blockIdx.x * 256 + threadIdx.x;  // == row*4 + kk
  const int row  = g >> 2;
  const int kk   = g & 3;
  const int lrow = threadIdx.x >> 2;                // row-in-block, 0..63

  __shared__ int   s_pts[64][25];
  __shared__ float s_m[64][4];
  __shared__ float s_c2[64][4];
  __shared__ float s_t[64][4];

  const float p0  = params[g * 3 + 0];
  const float p1f = params[g * 3 + 1];
  const float p2  = params[g * 3 + 2];

  // XLA logistic (exp-form): s = 1/(1+exp(-x)); mean = s*65535 (all f32)
  const float e32 = xla_vf32_exp(-p0);
  const float s32 = __fdiv_rn(1.0f, __fadd_rn(1.0f, e32));
  const float m   = __fmul_rn(s32, 65535.0f);

  const double xx = (double)p1f + 2.0;
  const double sp = fmax(xx, 0.0) + log1p(exp(-fabs(xx)));  // softplus, f64
  const float sig = (float)(1e-6 + ((sp + 1e-6) * 65536.0) * 0.2);
  const float c2  = -0.72134752044448170f / sig;  // -0.5*log2(e)/sig

  const float c1f = (float)(1.0 - 1e-6);
  int pt[6];
  pt[0] = (int)floorf(m);
  pt[1] = (int)ceilf(m);
  const float mr = rintf(m);                      // jnp.round: half-to-even
  float lowf = __fadd_rn(mr, -64.0f);
  if (lowf < 0.0f) lowf = 0.0f;
  if (__fadd_rn(mr, 64.0f) > 65536.0f) lowf = 65536.0f - 128.0f;
  const uint32_t base = (uint32_t)g * 2u;
#pragma unroll
  for (int r2 = 0; r2 < 2; ++r2) {
    const float u = jax_u01f(kr0, kr1, base + (uint32_t)r2);
    const float t = __fmul_rn(u, c1f);
    pt[2 + r2] = (int)floorf(__fadd_rn(__fmul_rn(t, 128.0f), lowf));
  }
#pragma unroll
  for (int r2 = 0; r2 < 2; ++r2) {
    const float u = jax_u01f(kg0, kg1, base + (uint32_t)r2);
    const float t = __fmul_rn(u, c1f);
    pt[4 + r2] = (int)floorf(__fmul_rn(t, 65536.0f));
  }

#pragma unroll
  for (int jj = 0; jj < 6; ++jj) s_pts[lrow][kk * 6 + jj] = pt[jj];
  s_m[lrow][kk]  = m;
  s_c2[lrow][kk] = c2;
  __syncthreads();

  uint32_t dup = 0u;
  {
    int p24[NPT];
#pragma unroll
    for (int j = 0; j < NPT; ++j) p24[j] = s_pts[lrow][j];
#pragma unroll
    for (int j = 1; j < NPT; ++j) {
      const int pj = p24[j];
      bool d = false;
#pragma unroll
      for (int j2 = 0; j2 < NPT - 1; ++j2) {
        if (j2 < j) d = d || (p24[j2] == pj);
      }
      if (d) dup |= (1u << j);
    }

    float S = 0.f;
#pragma unroll
    for (int j = 0; j < NPT; ++j) {
      const float live = ((dup >> j) & 1u) ? 0.0f : 1.0f;
      const float d = (float)p24[j] - m;
      S += live * exp2f(d * d * c2);   // huge-negative arg -> 0
    }
    s_t[lrow][kk] = __fdiv_rn(p2, S);
  }
  __syncthreads();

  {
    float mv[4], c2v[4], tv[4];
#pragma unroll
    for (int q = 0; q < 4; ++q) {
      mv[q]  = s_m[lrow][q];
      c2v[q] = s_c2[lrow][q];
      tv[q]  = s_t[lrow][q];
    }
    int* cb = tab + (size_t)row * 48;
    float* wb = (float*)(cb + 24);
#pragma unroll
    for (int jj = 0; jj < 6; ++jj) {
      const int j = kk * 6 + jj;
      const float pf = (float)pt[jj];
      float acc = 0.f;
#pragma unroll
      for (int q = 0; q < 4; ++q) {
        const float d = pf - mv[q];
        acc = fmaf(exp2f(d * d * c2v[q]), tv[q], acc);
      }
      float w = ((dup >> j) & 1u) ? 0.f : acc;
      if (pt[jj] == row) w = 0.f;  // rows == cols mask
      cb[j] = pt[jj];
      wb[j] = w;
    }
  }
}

// ---------------- Kernel B: EMB-sliced gather ----------------
// bid = rblock*8 + slice; under round-robin dispatch bid%8 == XCD, so XCD k
// only ever touches x[:, 16k:16(k+1)] = 4 MB -> L2-resident. Gather reads
// become L2 hits; x fetched from HBM once machine-wide instead of 8x.
// Thread (tid>>2, tid&3) = (row-in-block, float4-in-slice). Branchless 8-deep
// MLP chunks (R2/R8-validated; dead -> col 0, w=0: fmaf(0,..)=acc exact).
__global__ void __launch_bounds__(256) gkern(const float4* __restrict__ x4,
                                             const int* __restrict__ tab,
                                             float4* __restrict__ out4) {
  __shared__ int sws[64 * 49];   // stride 49: gcd(49*4/4,32)=1 -> conflict-free rows
  const int tid    = threadIdx.x;
  const int slice  = blockIdx.x & 7;
  const int rb     = (blockIdx.x >> 3) * 64;
  {
    const int* src = tab + (size_t)rb * 48;
#pragma unroll
    for (int t = tid; t < 64 * 48; t += 256) sws[(t / 48) * 49 + (t % 48)] = src[t];
  }
  __syncthreads();

  const int r   = tid >> 2;          // 0..63: row within block
  const int q   = tid & 3;           // 0..3: float4 within slice
  const int off = slice * 4 + q;     // float4 index within full row (0..31)
  const int* cb = sws + r * 49;
  const float* wb = (const float*)(cb + 24);

  float4 acc = make_float4(0.f, 0.f, 0.f, 0.f);
#pragma unroll
  for (int jc = 0; jc < NPT; jc += 8) {
    float wl[8];
    float4 xv[8];
#pragma unroll
    for (int u = 0; u < 8; ++u) {
      float w = wb[jc + u];
      int c = cb[jc + u];
      const bool live = fabsf(w) > 1e-6f;  // dup/self/underflow -> w==0 exactly
      wl[u] = live ? w : 0.0f;
      c = c > 65535 ? 65535 : c;           // f32 rr path can round to 65536; JAX clamps
      const int ce = live ? c : 0;         // dead -> hot line in this XCD's slice
      xv[u] = x4[(size_t)ce * 32 + off];
    }
#pragma unroll
    for (int u = 0; u < 8; ++u) {
      acc.x = fmaf(wl[u], xv[u].x, acc.x);
      acc.y = fmaf(wl[u], xv[u].y, acc.y);
      acc.z = fmaf(wl[u], xv[u].z, acc.z);
      acc.w = fmaf(wl[u], xv[u].w, acc.w);
    }
  }
  nfloat4 av; av.x = acc.x; av.y = acc.y; av.z = acc.z; av.w = acc.w;
  __builtin_nontemporal_store(av, (nfloat4*)(out4 + (size_t)(rb + r) * 32 + off));
}

extern "C" void kernel_launch(void* const* d_in, const int* in_sizes, int n_in,
                              void* d_out, int out_size, void* d_ws, size_t ws_size,
                              hipStream_t stream) {
  const float* params = (const float*)d_in[0];
  const float* x = (const float*)d_in[1];
  if (n_in >= 2 && in_sizes[0] > in_sizes[1]) {  // order guard
    const float* tmp = params; params = x; x = tmp;
  }
  int* d_tab = (int*)d_ws;

  // split(jax.random.key(42)), partitionable/foldlike: key_i = block(key, (0, i))
  uint32_t kr0, kr1, kg0, kg1;
  { uint32_t a0 = 0u, a1 = 0u; tf2x32(0u, 42u, a0, a1); kr0 = a0; kr1 = a1; }
  { uint32_t b0 = 0u, b1 = 1u; tf2x32(0u, 42u, b0, b1); kg0 = b0; kg1 = b1; }

  hipLaunchKernelGGL(wkern, dim3((C_NUM * 4) / 256), dim3(256), 0, stream,
                     params, d_tab, kr0, kr1, kg0, kg1);
  hipLaunchKernelGGL(gkern, dim3((C_NUM / 64) * 8), dim3(256), 0, stream,
                     (const float4*)x, d_tab, (float4*)d_out);
}

// Round 10
// 148.854 us; speedup vs baseline: 1.2228x; 1.2228x over previous
//
#include <hip/hip_runtime.h>
#include <stdint.h>
#include <math.h>

#define C_NUM 65536
#define NPT 24
#define RPB 64   // rows per block (R6/R8 best). R7 RPB=32: weight phase 2x dilated.
                 // R9 EMB-slice/XCD experiment: FETCH rose 232->293 MB — refuted.

typedef float nfloat4 __attribute__((ext_vector_type(4)));  // native vec for nontemporal builtin

static __host__ __device__ __forceinline__ void tf2x32(uint32_t k0, uint32_t k1,
                                                       uint32_t& x0, uint32_t& x1) {
  const uint32_t ks2 = k0 ^ k1 ^ 0x1BD11BDAu;
#define TF_R(r) { x0 += x1; x1 = (x1 << (r)) | (x1 >> (32 - (r))); x1 ^= x0; }
  x0 += k0; x1 += k1;
  TF_R(13) TF_R(15) TF_R(26) TF_R(6)
  x0 += k1;  x1 += ks2 + 1u;
  TF_R(17) TF_R(29) TF_R(16) TF_R(24)
  x0 += ks2; x1 += k0 + 2u;
  TF_R(13) TF_R(15) TF_R(26) TF_R(6)
  x0 += k0;  x1 += k1 + 3u;
  TF_R(17) TF_R(29) TF_R(16) TF_R(24)
  x0 += k1;  x1 += ks2 + 4u;
  TF_R(13) TF_R(15) TF_R(26) TF_R(6)
  x0 += ks2; x1 += k0 + 5u;
#undef TF_R
}

// f32 uniform [0,1): x64-OFF partitionable path. VALIDATED R1-R9 — do not touch.
__device__ __forceinline__ float jax_u01f(uint32_t ka, uint32_t kb, uint32_t idx) {
  uint32_t x0 = 0u, x1 = idx;
  tf2x32(ka, kb, x0, x1);
  const uint32_t bits = x0 ^ x1;
  return __fadd_rn(__uint_as_float((bits >> 9) | 0x3f800000u), -1.0f);
}

// XLA:CPU GenerateVF32Exp bitwise replica. VALIDATED — discrete decisions depend
// on exact bits. Do not touch.
__device__ __forceinline__ float xla_vf32_exp(float x) {
  float xc = fminf(x, 88.3762626647950f);     // exp_hi
  xc = fmaxf(xc, -87.3365478515625f);         // exp_lo
  const float fx = floorf(fmaf(xc, 1.44269504088896341f, 0.5f));
  float r = fmaf(fx, -0.693359375f, xc);      // cephes_exp_C1
  r = fmaf(fx, 2.12194440e-4f, r);            // -C2
  const float z = __fmul_rn(r, r);
  float y = 1.9875691500e-4f;                 // p0
  y = fmaf(y, r, 1.3981999507e-3f);           // p1
  y = fmaf(y, r, 8.3334519073e-3f);           // p2
  y = fmaf(y, r, 4.1665795894e-2f);           // p3
  y = fmaf(y, r, 1.6666665459e-1f);           // p4
  y = fmaf(y, r, 5.0000001201e-1f);           // p5
  y = fmaf(y, z, r);
  y = __fadd_rn(y, 1.0f);
  const int n = (int)fx;                      // our inputs: |fx| <= ~9, exact scale
  return __fmul_rn(y, __uint_as_float((uint32_t)(127 + n) << 23));
}

// ---------------- Fused kernel, 64 rows/block + MLP-8 gather (R8 best) --------
// Weight phase: 256 threads = 64 rows x 4 k (EXACT validated per-(row,k)
// pipeline). Gather phase: branchless 8-deep load chunks — dead entries load
// column 0 with w=0 (fmaf(0,finite,acc)=acc: bit-identical accumulation).
__global__ void __launch_bounds__(256) fkern(const float* __restrict__ params,
                                             const float4* __restrict__ x4,
                                             float4* __restrict__ out4,
                                             uint32_t kr0, uint32_t kr1,
                                             uint32_t kg0, uint32_t kg1) {
  __shared__ int   s_pts[RPB][25];   // +1 pad: 25%32 coprime -> conflict-light
  __shared__ float s_m[RPB][4];
  __shared__ float s_c2[RPB][4];
  __shared__ float s_t[RPB][4];
  __shared__ int   sws[RPB * 48];    // per-row: 24 cols + 24 f32 weights

  const int tid  = threadIdx.x;
  const int rb   = blockIdx.x * RPB;
  const int lrow = tid >> 2;         // 0..63
  const int kk   = tid & 3;          // 0..3
  const int row  = rb + lrow;
  const int g    = row * 4 + kk;

  // --- weight phase part 1: params -> mean/sigma + 6 points (all 256 threads) ---
  const float p0  = params[g * 3 + 0];
  const float p1f = params[g * 3 + 1];
  const float p2  = params[g * 3 + 2];

  // XLA logistic (exp-form): s = 1/(1+exp(-x)); mean = s*65535 (all f32)
  const float e32 = xla_vf32_exp(-p0);
  const float s32 = __fdiv_rn(1.0f, __fadd_rn(1.0f, e32));
  const float m   = __fmul_rn(s32, 65535.0f);

  const double xx = (double)p1f + 2.0;
  const double sp = fmax(xx, 0.0) + log1p(exp(-fabs(xx)));  // softplus, f64
  const float sig = (float)(1e-6 + ((sp + 1e-6) * 65536.0) * 0.2);
  const float c2  = -0.72134752044448170f / sig;  // -0.5*log2(e)/sig

  const float c1f = (float)(1.0 - 1e-6);
  int pt[6];
  pt[0] = (int)floorf(m);
  pt[1] = (int)ceilf(m);
  const float mr = rintf(m);                      // jnp.round: half-to-even
  float lowf = __fadd_rn(mr, -64.0f);
  if (lowf < 0.0f) lowf = 0.0f;
  if (__fadd_rn(mr, 64.0f) > 65536.0f) lowf = 65536.0f - 128.0f;
  const uint32_t base = (uint32_t)g * 2u;
#pragma unroll
  for (int r2 = 0; r2 < 2; ++r2) {
    const float u = jax_u01f(kr0, kr1, base + (uint32_t)r2);
    const float t = __fmul_rn(u, c1f);
    pt[2 + r2] = (int)floorf(__fadd_rn(__fmul_rn(t, 128.0f), lowf));
  }
#pragma unroll
  for (int r2 = 0; r2 < 2; ++r2) {
    const float u = jax_u01f(kg0, kg1, base + (uint32_t)r2);
    const float t = __fmul_rn(u, c1f);
    pt[4 + r2] = (int)floorf(__fmul_rn(t, 65536.0f));
  }

#pragma unroll
  for (int jj = 0; jj < 6; ++jj) s_pts[lrow][kk * 6 + jj] = pt[jj];
  s_m[lrow][kk]  = m;
  s_c2[lrow][kk] = c2;
  __syncthreads();

  // --- weight phase part 2: dup mask + per-k normalization ---
  uint32_t dup = 0u;
  {
    int p24[NPT];
#pragma unroll
    for (int j = 0; j < NPT; ++j) p24[j] = s_pts[lrow][j];
#pragma unroll
    for (int j = 1; j < NPT; ++j) {
      const int pj = p24[j];
      bool d = false;
#pragma unroll
      for (int j2 = 0; j2 < NPT - 1; ++j2) {
        if (j2 < j) d = d || (p24[j2] == pj);
      }
      if (d) dup |= (1u << j);
    }

    float S = 0.f;
#pragma unroll
    for (int j = 0; j < NPT; ++j) {
      const float live = ((dup >> j) & 1u) ? 0.0f : 1.0f;
      const float d = (float)p24[j] - m;
      S += live * exp2f(d * d * c2);   // huge-negative arg -> 0
    }
    s_t[lrow][kk] = __fdiv_rn(p2, S);
  }
  __syncthreads();

  // --- weight phase part 3: my 6 weights -> LDS tab ---
  {
    float mv[4], c2v[4], tv[4];
#pragma unroll
    for (int q = 0; q < 4; ++q) {
      mv[q]  = s_m[lrow][q];
      c2v[q] = s_c2[lrow][q];
      tv[q]  = s_t[lrow][q];
    }
    int* cb = sws + lrow * 48;
    float* wb = (float*)(cb + 24);
#pragma unroll
    for (int jj = 0; jj < 6; ++jj) {
      const int j = kk * 6 + jj;
      const float pf = (float)pt[jj];
      float acc = 0.f;
#pragma unroll
      for (int q = 0; q < 4; ++q) {
        const float d = pf - mv[q];
        acc = fmaf(exp2f(d * d * c2v[q]), tv[q], acc);
      }
      float w = ((dup >> j) & 1u) ? 0.f : acc;
      if (pt[jj] == row) w = 0.f;  // rows == cols mask
      cb[j] = pt[jj];
      wb[j] = w;
    }
  }
  __syncthreads();

  // --- gather phase: branchless 8-deep chunks (R2/R8-validated form) ---
  const int sub  = tid >> 5;
  const int lane = tid & 31;
#pragma unroll
  for (int it = 0; it < RPB / 8; ++it) {
    const int r = it * 8 + sub;
    const int* cb = sws + r * 48;
    const float* wb = (const float*)(cb + 24);

    float4 acc = make_float4(0.f, 0.f, 0.f, 0.f);
#pragma unroll
    for (int jc = 0; jc < NPT; jc += 8) {
      float wl[8];
      float4 xv[8];
#pragma unroll
      for (int u = 0; u < 8; ++u) {
        float w = wb[jc + u];
        int c = cb[jc + u];
        const bool live = fabsf(w) > 1e-6f;  // dup/self/underflow -> w==0 exactly
        wl[u] = live ? w : 0.0f;
        c = c > 65535 ? 65535 : c;           // f32 rr path can round to 65536; JAX clamps
        const int ce = live ? c : 0;         // dead -> hot line, no fabric traffic
        xv[u] = x4[(size_t)ce * 32 + lane];
      }
#pragma unroll
      for (int u = 0; u < 8; ++u) {
        acc.x = fmaf(wl[u], xv[u].x, acc.x);
        acc.y = fmaf(wl[u], xv[u].y, acc.y);
        acc.z = fmaf(wl[u], xv[u].z, acc.z);
        acc.w = fmaf(wl[u], xv[u].w, acc.w);
      }
    }
    nfloat4 av; av.x = acc.x; av.y = acc.y; av.z = acc.z; av.w = acc.w;
    __builtin_nontemporal_store(av, (nfloat4*)(out4 + (size_t)(rb + r) * 32 + lane));
  }
}

extern "C" void kernel_launch(void* const* d_in, const int* in_sizes, int n_in,
                              void* d_out, int out_size, void* d_ws, size_t ws_size,
                              hipStream_t stream) {
  const float* params = (const float*)d_in[0];
  const float* x = (const float*)d_in[1];
  if (n_in >= 2 && in_sizes[0] > in_sizes[1]) {  // order guard
    const float* tmp = params; params = x; x = tmp;
  }
  (void)d_ws; (void)ws_size;

  // split(jax.random.key(42)), partitionable/foldlike: key_i = block(key, (0, i))
  uint32_t kr0, kr1, kg0, kg1;
  { uint32_t a0 = 0u, a1 = 0u; tf2x32(0u, 42u, a0, a1); kr0 = a0; kr1 = a1; }
  { uint32_t b0 = 0u, b1 = 1u; tf2x32(0u, 42u, b0, b1); kg0 = b0; kg1 = b1; }

  hipLaunchKernelGGL(fkern, dim3(C_NUM / RPB), dim3(256), 0, stream,
                     params, (const float4*)x, (float4*)d_out, kr0, kr1, kg0, kg1);
}